// Round 10
// baseline (126.294 us; speedup 1.0000x reference)
//
#include <hip/hip_runtime.h>
#include <cmath>

// Conductance-based LIF scan: T=512 steps, N=65536 neurons.
// R9: zero-barrier async self-staging with STORE-ORDER-ROBUST counted
// vmcnt. Robust rule: before consuming batch B, wait vmcnt(K) where
// K = #LOADS issued after B's last load. Loads retire in order among
// themselves (m135), so if B's last load were still outstanding, all K
// younger loads would be too -> outstanding >= K+1 > K. No assumption
// about store retirement order (R8's bug). Ring = 16 slots = 4 batches
// in flight (48 KB LDS) -> K = 36 uniformly; at wait time expected
// outstanding ~= 32 (newest 2 refills + recent stores) < 36, so the
// wait is usually free, and each batch gets ~3 groups (~1500+ cy) of
// flight time > 900 cy HBM latency.
//
// Numerics identical to R5/R7 (passed, absmax 0.00390625): FMA-contracted,
// rcp-div, __expf. gA == 0 (ADAPT_INC==0), elided.

__device__ __forceinline__ void gload_lds(const float* g, float* l) {
    __builtin_amdgcn_global_load_lds(
        (const __attribute__((address_space(1))) unsigned int*)(const void*)g,
        (__attribute__((address_space(3))) unsigned int*)(void*)l,
        4, 0, 0);
}

#define WAITV(n) asm volatile("s_waitcnt vmcnt(" #n ")" ::: "memory")

__global__ __launch_bounds__(256, 1) void lif_scan(
    const float* __restrict__ g_exc,
    const float* __restrict__ g_inh,
    const float* __restrict__ noise,
    const float* __restrict__ v_th,
    const float* __restrict__ tau_ref,
    float* __restrict__ out_spk,   // d_out[0 .. T*N)
    float* __restrict__ out_mem,   // d_out[T*N .. 2*T*N)
    int N, int T,
    float cGE, float cGI, float cALPHA, float cSIGMA)
{
    __shared__ float smem[16][3][256];   // [slot][array][lane] = 48 KiB

    const int tid = threadIdx.x;
    const int wq  = (tid >> 6) << 6;            // this wave's LDS quarter base
    const int n   = blockIdx.x * 256 + tid;

    const float vth = v_th[n];
    const float trf = tau_ref[n];

    float v = 0.f, gE = 0.f, gI = 0.f, ref = 0.f, ou = 0.f;

    // stage steps t0..t0+3 into ring slots sb..sb+3 (12 async loads)
    auto issueB = [&](int t0, int sb) {
        #pragma unroll
        for (int k = 0; k < 4; ++k) {
            const size_t row = (size_t)(t0 + k) * (size_t)N + (size_t)n;
            gload_lds(g_exc + row, &smem[sb + k][0][wq]);
            gload_lds(g_inh + row, &smem[sb + k][1][wq]);
            gload_lds(noise + row, &smem[sb + k][2][wq]);
        }
    };

    auto step = [&](float ge_in, float gi_in, float z, int tt) {
        gE = __builtin_fmaf(gE, cGE, ge_in);
        gI = __builtin_fmaf(gI, cGI, gi_in);

        const float gt  = 1.0f + gE + gI;
        const float num = __builtin_fmaf(gI, -0.5f, gE * 3.0f);
        const float vinf = num * __builtin_amdgcn_rcpf(gt);

        const float decay = __expf(-0.05f * gt);

        v = __builtin_fmaf(v - vinf, decay, vinf);

        ou = __builtin_fmaf(ou, cALPHA, cSIGMA * z);
        v = v + ou;

        const bool in_ref = (ref > 0.0f);
        const bool spike  = (v >= vth) && (!in_ref);
        v = (in_ref || spike) ? 0.0f : v;
        ref = spike ? trf : fmaxf(ref - 1.0f, 0.0f);

        const size_t off = (size_t)tt * (size_t)N + (size_t)n;
        __builtin_nontemporal_store(spike ? 1.0f : 0.0f, out_spk + off);
        __builtin_nontemporal_store(v, out_mem + off);
    };

    // one 4-step group: read slots sb..sb+3, refill them for t0+16,
    // compute 4 steps (+8 NT stores)
    auto group = [&](int t0, int sb, bool issue) {
        float vals[12];
        #pragma unroll
        for (int k = 0; k < 4; ++k) {
            vals[k * 3 + 0] = smem[sb + k][0][tid];
            vals[k * 3 + 1] = smem[sb + k][1][tid];
            vals[k * 3 + 2] = smem[sb + k][2][tid];
        }
        // slot data in VGPRs before its refill is issued
        asm volatile("s_waitcnt lgkmcnt(0)" ::: "memory");
        if (issue) issueB(t0 + 16, sb);
        #pragma unroll
        for (int k = 0; k < 4; ++k)
            step(vals[k * 3 + 0], vals[k * 3 + 1], vals[k * 3 + 2], t0 + k);
    };

    // prologue: 4 batches in flight (slots 0-3, 4-7, 8-11, 12-15)
    issueB(0, 0);
    issueB(4, 4);
    issueB(8, 8);
    issueB(12, 12);

    // groups g=0..123 all have exactly 36 loads newer than their target
    // batch (3 in-flight refills x 12), because refills keep 1:1 pace.
    // p=0..30 covers t0 = 0..492; group at t0 refills t0+16 (<= 508).
    for (int p = 0; p <= 30; ++p) {
        WAITV(36); group(16 * p,      0,  true);
        WAITV(36); group(16 * p + 4,  4,  true);
        WAITV(36); group(16 * p + 8,  8,  true);
        WAITV(36); group(16 * p + 12, 12, true);
    }
    // epilogue groups 124..127 (no refill): newer loads = 36/24/12/0
    WAITV(36); group(496, 0,  false);
    WAITV(24); group(500, 4,  false);
    WAITV(12); group(504, 8,  false);
    WAITV(0);  group(508, 12, false);
}

extern "C" void kernel_launch(void* const* d_in, const int* in_sizes, int n_in,
                              void* d_out, int out_size, void* d_ws, size_t ws_size,
                              hipStream_t stream) {
    const float* g_exc   = (const float*)d_in[0];
    const float* g_inh   = (const float*)d_in[1];
    const float* noise   = (const float*)d_in[2];
    const float* v_th    = (const float*)d_in[3];
    const float* tau_ref = (const float*)d_in[4];

    const int N = in_sizes[3];            // 65536
    const int T = in_sizes[0] / N;        // 512

    float* out_spk = (float*)d_out;
    float* out_mem = (float*)d_out + (size_t)T * (size_t)N;

    // Constants computed in double exactly as the Python reference does.
    const double ge_decay = exp(-1.0 / 5.0);
    const double gi_decay = exp(-1.0 / 10.0);
    const double ou_alpha = exp(-1.0 / 5.0);
    const double ou_sigma = 0.02 * sqrt(1.0 - ou_alpha * ou_alpha);

    const int block = 256;
    const int grid = (N + block - 1) / block;   // 256 blocks = 1024 waves
    lif_scan<<<grid, block, 0, stream>>>(
        g_exc, g_inh, noise, v_th, tau_ref, out_spk, out_mem,
        N, T,
        (float)ge_decay, (float)gi_decay, (float)ou_alpha, (float)ou_sigma);
}